// Round 28
// baseline (148.532 us; speedup 1.0000x reference)
//
#include <hip/hip_runtime.h>
#include <cstdint>

#define BB 16
#define MM 128
#define TT 12000
constexpr int BT = BB * TT; // 192000

// Q4-interleaved scan layout: element (row b, pos t), t=4g+j lives at
// q[(g*16 + b)*4 + j]. Group = 256 B. SB8 = 8 groups = 2048 B.
// Full-wave load (64 lanes x 16 B) covers 4 groups: lane 16k+r holds
// (group G+k, row r). 378 SBs scanned (375 real + 3 pad).

// K1: per-column stats over the M axis, sequential in m (reference order).
// anti-fma via `#pragma clang fp contract(off)` (proven round 13).
__global__ void k1_colstats(const float* __restrict__ mel,
                            float* __restrict__ ssq,
                            float* __restrict__ dotv,
                            float* __restrict__ cmean,
                            unsigned int* __restrict__ counts) {
    if (blockIdx.x == 0 && blockIdx.y == 0 && threadIdx.x < 8)
        counts[threadIdx.x] = 0u;
    const int b = blockIdx.y;
    const int t = blockIdx.x * blockDim.x + threadIdx.x;
    if (t >= TT) return;
    const float* base = mel + (size_t)b * MM * TT;
    float accd = 0.f, accq = 0.f, accs = 0.f;
    {
#pragma clang fp contract(off)
        for (int m = 0; m < MM; ++m) {
            const float* rowp = base + (size_t)m * TT;
            float cur = rowp[t];
            float prev = (t > 0) ? rowp[t - 1] : 0.f;
            accd += prev * cur;
            accq += cur * cur;
            accs += cur;
        }
    }
    size_t i = (size_t)b * TT + t;
    ssq[i] = accq; dotv[i] = accd; cmean[i] = accs * (1.0f / MM);
}

// kA: temporal = 1 - std(smooth, ddof=1). Row staged to LDS once.
__global__ void kA_temporal(const float* __restrict__ cmean,
                            float* __restrict__ temporal) {
    const int b = blockIdx.x;
    const int tid = threadIdx.x;
    __shared__ __align__(16) float row_s[TT];
    __shared__ float red[256];
    __shared__ float mean_s;
    const float4* c4 = (const float4*)(cmean + (size_t)b * TT);
    float4* r4 = (float4*)row_s;
    for (int i = tid; i < TT / 4; i += 256) r4[i] = c4[i];
    __syncthreads();

    float s = 0.f;
    for (int t = tid; t < TT; t += 256) {
        float v = 0.f;
        int lo = t - 2 < 0 ? 0 : t - 2;
        int hi = t + 2 >= TT ? TT - 1 : t + 2;
        for (int j = lo; j <= hi; ++j) v += row_s[j];
        s += v / 5.0f;
    }
    red[tid] = s; __syncthreads();
    for (int o = 128; o > 0; o >>= 1) {
        if (tid < o) red[tid] += red[tid + o];
        __syncthreads();
    }
    if (tid == 0) mean_s = red[0] / (float)TT;
    __syncthreads();
    float mean = mean_s;
    float ss = 0.f;
    for (int t = tid; t < TT; t += 256) {
        float v = 0.f;
        int lo = t - 2 < 0 ? 0 : t - 2;
        int hi = t + 2 >= TT ? TT - 1 : t + 2;
        for (int j = lo; j <= hi; ++j) v += row_s[j];
        float sm = v / 5.0f - mean;
        ss += sm * sm;
    }
    red[tid] = ss; __syncthreads();
    for (int o = 128; o > 0; o >>= 1) {
        if (tid < o) red[tid] += red[tid + o];
        __syncthreads();
    }
    if (tid == 0) {
        float var = red[0] / (float)(TT - 1);
        temporal[b] = 1.0f - sqrtf(var);
    }
}

// kB: cons — same arithmetic as the passing version; additionally writes
// the Q4-interleaved copy for the scan (same value, extra store only).
__global__ void kB_cons(const float* __restrict__ ssq,
                        const float* __restrict__ dotv,
                        const float* __restrict__ spec,
                        const float* __restrict__ temporal,
                        const float* __restrict__ wraw,
                        float* __restrict__ cons,
                        float* __restrict__ consq) {
    const int idx = blockIdx.x * 256 + threadIdx.x;
    const int b = idx / TT;
    const int t = idx - b * TT;
    float x0 = wraw[0], x1 = wraw[1], x2 = wraw[2];
    float mx = fmaxf(x0, fmaxf(x1, x2));
    float e0 = expf(x0 - mx), e1 = expf(x1 - mx), e2 = expf(x2 - mx);
    float es = (e0 + e1) + e2;
    float w0 = e0 / es, w1 = e1 / es, w2 = e2 / es;
    float mel_sim, spec_sim;
    if (t == 0) { mel_sim = 0.f; spec_sim = 1.f; }
    else {
        float na = fmaxf(sqrtf(ssq[idx - 1]), 1e-8f);
        float nb = fmaxf(sqrtf(ssq[idx]),     1e-8f);
        float den = na * nb; asm volatile("" : "+v"(den));
        mel_sim = dotv[idx] / den;
        float d = fabsf(spec[idx] - spec[idx - 1]);
        spec_sim = 1.0f / (1.0f + d);
    }
    float pa = w0 * mel_sim;     asm volatile("" : "+v"(pa));
    float pb = w1 * spec_sim;    asm volatile("" : "+v"(pb));
    float pc = w2 * temporal[b]; asm volatile("" : "+v"(pc));
    float c = (pa + pb) + pc;
    cons[idx] = c;
    consq[((t >> 2) * 16 + b) * 4 + (t & 3)] = c;
}

// 4 chained adds: carry enters via P, leaves in d (bitwise ref order).
#define QCH(P, a, b, c, d) \
    "v_add_f32 v" a ", v" P ", v" a "\n\t" \
    "v_add_f32 v" b ", v" a ", v" b "\n\t" \
    "v_add_f32 v" c ", v" b ", v" c "\n\t" \
    "v_add_f32 v" d ", v" c ", v" d "\n\t"

// One SB8 with FULL-WAVE loads: 2 loads/SB8 (vs 8) -> 12 SB8s fit the
// ~24-outstanding-load/wave HW cap -> latency fully covered.
// vmcnt(50): this SB's 2 loads issued 6 SBs back; 5 SBs x 10 ops younger.
// Redistribution: groups 1-3 (5-7) of load A (B) live in lanes 16k+r;
// 12+12 ds_bpermute_b32 pull them into scan lanes (addr %4/%5/%6 =
// ((l&15)+16k)*4), staggered exact lgkm waits 8/4/0 per batch.
// Groups 0/4 used direct from load-dest. Carry snapshot at SB end
// (round-5 WAR discipline). All 64 lanes store; lanes 16-63 write to a
// dump region (svoff offset) — no exec masking needed.
#define SBW(QA0,QA1,QA2,QA3, QB0,QB1,QB2,QB3) \
    "s_waitcnt vmcnt(50)\n\t" \
    "ds_bpermute_b32 v96,  %4, v" QA0 "\n\t" \
    "ds_bpermute_b32 v97,  %4, v" QA1 "\n\t" \
    "ds_bpermute_b32 v98,  %4, v" QA2 "\n\t" \
    "ds_bpermute_b32 v99,  %4, v" QA3 "\n\t" \
    "ds_bpermute_b32 v100, %5, v" QA0 "\n\t" \
    "ds_bpermute_b32 v101, %5, v" QA1 "\n\t" \
    "ds_bpermute_b32 v102, %5, v" QA2 "\n\t" \
    "ds_bpermute_b32 v103, %5, v" QA3 "\n\t" \
    "ds_bpermute_b32 v104, %6, v" QA0 "\n\t" \
    "ds_bpermute_b32 v105, %6, v" QA1 "\n\t" \
    "ds_bpermute_b32 v106, %6, v" QA2 "\n\t" \
    "ds_bpermute_b32 v107, %6, v" QA3 "\n\t" \
    QCH("43", QA0, QA1, QA2, QA3) \
    "s_waitcnt lgkmcnt(8)\n\t" \
    QCH(QA3, "96", "97", "98", "99") \
    "s_waitcnt lgkmcnt(4)\n\t" \
    QCH("99", "100", "101", "102", "103") \
    "s_waitcnt lgkmcnt(0)\n\t" \
    QCH("103", "104", "105", "106", "107") \
    "ds_bpermute_b32 v108, %4, v" QB0 "\n\t" \
    "ds_bpermute_b32 v109, %4, v" QB1 "\n\t" \
    "ds_bpermute_b32 v110, %4, v" QB2 "\n\t" \
    "ds_bpermute_b32 v111, %4, v" QB3 "\n\t" \
    "ds_bpermute_b32 v112, %5, v" QB0 "\n\t" \
    "ds_bpermute_b32 v113, %5, v" QB1 "\n\t" \
    "ds_bpermute_b32 v114, %5, v" QB2 "\n\t" \
    "ds_bpermute_b32 v115, %5, v" QB3 "\n\t" \
    "ds_bpermute_b32 v116, %6, v" QB0 "\n\t" \
    "ds_bpermute_b32 v117, %6, v" QB1 "\n\t" \
    "ds_bpermute_b32 v118, %6, v" QB2 "\n\t" \
    "ds_bpermute_b32 v119, %6, v" QB3 "\n\t" \
    QCH("107", QB0, QB1, QB2, QB3) \
    "s_waitcnt lgkmcnt(8)\n\t" \
    QCH(QB3, "108", "109", "110", "111") \
    "s_waitcnt lgkmcnt(4)\n\t" \
    QCH("111", "112", "113", "114", "115") \
    "s_waitcnt lgkmcnt(0)\n\t" \
    QCH("115", "116", "117", "118", "119") \
    "v_mov_b32 v43, v119\n\t" \
    "global_store_dwordx4 v40, v[" QA0 ":" QA3 "], %1 offset:0\n\t" \
    "global_store_dwordx4 v40, v[96:99],   %1 offset:256\n\t" \
    "global_store_dwordx4 v40, v[100:103], %1 offset:512\n\t" \
    "global_store_dwordx4 v40, v[104:107], %1 offset:768\n\t" \
    "global_store_dwordx4 v40, v[" QB0 ":" QB3 "], %1 offset:1024\n\t" \
    "global_store_dwordx4 v40, v[108:111], %1 offset:1280\n\t" \
    "global_store_dwordx4 v40, v[112:115], %1 offset:1536\n\t" \
    "global_store_dwordx4 v40, v[116:119], %1 offset:1792\n\t" \
    "global_load_dwordx4 v[" QA0 ":" QA3 "], v42, %0 offset:0\n\t" \
    "global_load_dwordx4 v[" QB0 ":" QB3 "], v42, %0 offset:1024\n\t" \
    "v_add_u32 v40, 0x800, v40\n\t" \
    "v_add_u32 v42, 0x800, v42\n\t"

// Prologue fill for one ring slot (2 full-wave loads + bump).
#define PROW(QA0,QA1,QA2,QA3, QB0,QB1,QB2,QB3) \
    "global_load_dwordx4 v[" QA0 ":" QA3 "], v42, %0 offset:0\n\t" \
    "global_load_dwordx4 v[" QB0 ":" QB3 "], v42, %0 offset:1024\n\t" \
    "v_add_u32 v42, 0x800, v42\n\t"

// Ring slots (QA,QB quads): s0..s5 in v48..v95.
#define S0 "48","49","50","51","52","53","54","55"
#define S1 "56","57","58","59","60","61","62","63"
#define S2 "64","65","66","67","68","69","70","71"
#define S3 "72","73","74","75","76","77","78","79"
#define S4 "80","81","82","83","84","85","86","87"
#define S5 "88","89","90","91","92","93","94","95"
#define XP(M, ...) M(__VA_ARGS__)

// kC: 16-row SIMT scan with full-wave loads + bpermute redistribution.
// 63 iters x 6 slots = 378 SBs (375 real). Warmers on waves 1-3.
__global__ void __launch_bounds__(256)
kC_scan16(const float* __restrict__ consq,
          float* __restrict__ CSq) {
    const int tid = threadIdx.x;
    if (tid >= 64) {
        // warmers: stream consq into the local XCD L2 (decoupled, no sync).
        const float4* s4 = (const float4*)consq;
        const int lane = tid - 64;
        for (int it = 0; it < 32; ++it) {
            float4 tmp[8];
#pragma unroll
            for (int i = 0; i < 8; ++i)
                tmp[i] = s4[(size_t)it * 1536 + lane + 192 * i];
#pragma unroll
            for (int i = 0; i < 8; ++i)
                asm volatile("" :: "v"(tmp[i].x), "v"(tmp[i].y),
                                   "v"(tmp[i].z), "v"(tmp[i].w));
        }
        return;
    }
    // wave 0: ALL 64 lanes enter the asm.
    uint32_t lvoff = (uint32_t)(tid * 16);                    // load offset
    uint32_t svoff = (uint32_t)(((tid >> 4) ? 786432u : 0u)   // dump for k>0
                                + (tid & 15) * 16);           // store offset
    uint32_t a1 = (uint32_t)(((tid & 15) + 16) * 4);
    uint32_t a2 = (uint32_t)(((tid & 15) + 32) * 4);
    uint32_t a3 = (uint32_t)(((tid & 15) + 48) * 4);
    asm volatile(
        "v_mov_b32 v40, %3\n\t"     // store byte offset
        "v_mov_b32 v42, %2\n\t"     // load byte offset
        "v_mov_b32 v43, 0\n\t"      // carry
        // prologue: fill 6-slot ring (12 full-wave loads)
        XP(PROW, S0) XP(PROW, S1) XP(PROW, S2)
        XP(PROW, S3) XP(PROW, S4) XP(PROW, S5)
        "s_waitcnt vmcnt(0)\n\t"
        "s_mov_b32 s20, 63\n\t"     // 63 x 6 = 378 SBs
        "3:\n\t"
        XP(SBW, S0)
        XP(SBW, S1)
        XP(SBW, S2)
        XP(SBW, S3)
        XP(SBW, S4)
        XP(SBW, S5)
        "s_sub_u32 s20, s20, 1\n\t"
        "s_cmp_lg_u32 s20, 0\n\t"
        "s_cbranch_scc1 3b\n\t"
        "s_waitcnt vmcnt(0) lgkmcnt(0)\n\t"
        :
        : "s"(consq), "s"(CSq), "v"(lvoff), "v"(svoff),
          "v"(a1), "v"(a2), "v"(a3)
        : "v40", "v42", "v43",
          "v48","v49","v50","v51","v52","v53","v54","v55",
          "v56","v57","v58","v59","v60","v61","v62","v63",
          "v64","v65","v66","v67","v68","v69","v70","v71",
          "v72","v73","v74","v75","v76","v77","v78","v79",
          "v80","v81","v82","v83","v84","v85","v86","v87",
          "v88","v89","v90","v91","v92","v93","v94","v95",
          "v96","v97","v98","v99","v100","v101","v102","v103",
          "v104","v105","v106","v107","v108","v109","v110","v111",
          "v112","v113","v114","v115","v116","v117","v118","v119",
          "s20", "scc", "memory");
}

// kD: flags ONLY — per-iteration "any nonzero adjustment" on the
// never-done trajectory. k_final recomputes step/cand (bitwise same).
__global__ void kD_flags(const float* __restrict__ cons,
                         const float* __restrict__ CSq,
                         const float* __restrict__ init,
                         unsigned int* __restrict__ counts) {
    const int idx = blockIdx.x * 256 + threadIdx.x;
    const int b = idx / TT;
    const int t = idx - b * TT;
    __shared__ unsigned sflag[5];
    if (threadIdx.x < 5) sflag[threadIdx.x] = 0u;
    __syncthreads();

    int lo = t - 2; if (lo < 0) lo = 0;
    int hi = t + 3; if (hi > TT) hi = TT;
    int uh = hi - 1;
    float csH = CSq[((uh >> 2) * 16 + b) * 4 + (uh & 3)];
    float csL = 0.f;
    if (lo > 0) {
        int ul = lo - 1;
        csL = CSq[((ul >> 2) * 16 + b) * 4 + (ul & 3)];
    }
    float local = (csH - csL) / (float)(hi - lo);
    float dir = (local > 0.7f) ? -0.1f : ((local < 0.4f) ? 0.1f : 0.0f);
    bool interior = (t >= 1) && (t <= TT - 2);
    float step = interior ? dir : 0.0f;
    float g = (t == 0) ? 0.f : fabsf(cons[idx] - cons[idx - 1]);
    float cand = (g > 0.15f) ? 1.f : 0.f;
    float r = init[idx];
    bool nz[5];
#pragma unroll
    for (int j = 0; j < 5; ++j) {
        float adj = (fmaxf(cand, r) > 0.5f) ? step : 0.0f;
        nz[j] = (adj != 0.0f);
        r = fminf(fmaxf(r + adj, 0.0f), 1.0f);
    }
    const int lane = threadIdx.x & 63;
#pragma unroll
    for (int j = 0; j < 5; ++j) {
        unsigned long long mb = __ballot(nz[j]);
        if (lane == 0 && mb) atomicOr(&sflag[j], 1u);   // LDS-scope, cheap
    }
    __syncthreads();
    if (threadIdx.x < 5 && sflag[threadIdx.x]) counts[threadIdx.x] = 1u;
}

// K_final: recompute step/cand (bitwise same as kD) and replay the 5-iter
// trajectory, freezing at the first iteration whose flag is 0.
__global__ void k_final(const float* __restrict__ cons,
                        const float* __restrict__ CSq,
                        const float* __restrict__ init,
                        const unsigned int* __restrict__ counts,
                        float* __restrict__ outp) {
    const int idx = blockIdx.x * 256 + threadIdx.x;
    const int b = idx / TT;
    const int t = idx - b * TT;

    int lo = t - 2; if (lo < 0) lo = 0;
    int hi = t + 3; if (hi > TT) hi = TT;
    int uh = hi - 1;
    float csH = CSq[((uh >> 2) * 16 + b) * 4 + (uh & 3)];
    float csL = 0.f;
    if (lo > 0) {
        int ul = lo - 1;
        csL = CSq[((ul >> 2) * 16 + b) * 4 + (ul & 3)];
    }
    float local = (csH - csL) / (float)(hi - lo);
    float dir = (local > 0.7f) ? -0.1f : ((local < 0.4f) ? 0.1f : 0.0f);
    bool interior = (t >= 1) && (t <= TT - 2);
    float step = interior ? dir : 0.0f;
    float g = (t == 0) ? 0.f : fabsf(cons[idx] - cons[idx - 1]);
    float cand = (g > 0.15f) ? 1.f : 0.f;

    float r = init[idx];
    unsigned c[5];
#pragma unroll
    for (int j = 0; j < 5; ++j) c[j] = counts[j];
#pragma unroll
    for (int j = 0; j < 5; ++j) {
        if (c[j] == 0u) break;
        float adj = (fmaxf(cand, r) > 0.5f) ? step : 0.0f;
        r = fminf(fmaxf(r + adj, 0.0f), 1.0f);
    }
    outp[idx] = r;
}

extern "C" void kernel_launch(void* const* d_in, const int* in_sizes, int n_in,
                              void* d_out, int out_size, void* d_ws, size_t ws_size,
                              hipStream_t stream) {
    const float* mel  = (const float*)d_in[0];
    const float* spec = (const float*)d_in[1];
    const float* init = (const float*)d_in[2];
    const float* wts  = (const float*)d_in[3];

    float* ws = (float*)d_ws;
    float* ssq   = ws;                 // 192000
    float* dotv  = ws + 192000;        // 192000
    float* cmean = ws + 384000;        // 192000
    float* cons  = ws + 576000;        // 192000 (row-major)
    float* consq = ws + 768000;        // 196608 (Q4, 3072-group pad: load lookahead)
    float* CSq   = ws + 964608;        // 196608 (Q4; real 3000 groups + pad)
    // dump region for lanes 16-63's stores: 196608 floats at CSq + 196608
    float* temporal = ws + 1357824;    // 16
    unsigned int* counts = (unsigned int*)(ws + 1357840); // 8 u32

    dim3 g1((TT + 255) / 256, BB);
    k1_colstats<<<g1, 256, 0, stream>>>(mel, ssq, dotv, cmean, counts);
    kA_temporal<<<BB, 256, 0, stream>>>(cmean, temporal);
    kB_cons<<<BT / 256, 256, 0, stream>>>(ssq, dotv, spec, temporal, wts, cons, consq);
    kC_scan16<<<1, 256, 0, stream>>>(consq, CSq);
    kD_flags<<<BT / 256, 256, 0, stream>>>(cons, CSq, init, counts);
    k_final<<<BT / 256, 256, 0, stream>>>(cons, CSq, init, counts, (float*)d_out);
}

// Round 29
// 122.683 us; speedup vs baseline: 1.2107x; 1.2107x over previous
//
#include <hip/hip_runtime.h>
#include <cstdint>

#define BB 16
#define MM 128
#define TT 12000
constexpr int BT = BB * TT; // 192000

// Q4-interleaved scan layout: element (row b, pos t), t=4g+j lives at
// q[(g*16 + b)*4 + j]  (one float4 per (group, row); 16 rows contiguous
// per group -> a 16-lane quad access covers 256 contiguous bytes).

// K1: per-column stats over the M axis, sequential in m (reference order).
// anti-fma via `#pragma clang fp contract(off)` (proven round 13).
__global__ void k1_colstats(const float* __restrict__ mel,
                            float* __restrict__ ssq,
                            float* __restrict__ dotv,
                            float* __restrict__ cmean,
                            unsigned int* __restrict__ counts) {
    if (blockIdx.x == 0 && blockIdx.y == 0 && threadIdx.x < 8)
        counts[threadIdx.x] = 0u;
    const int b = blockIdx.y;
    const int t = blockIdx.x * blockDim.x + threadIdx.x;
    if (t >= TT) return;
    const float* base = mel + (size_t)b * MM * TT;
    float accd = 0.f, accq = 0.f, accs = 0.f;
    {
#pragma clang fp contract(off)
        for (int m = 0; m < MM; ++m) {
            const float* rowp = base + (size_t)m * TT;
            float cur = rowp[t];
            float prev = (t > 0) ? rowp[t - 1] : 0.f;
            accd += prev * cur;
            accq += cur * cur;
            accs += cur;
        }
    }
    size_t i = (size_t)b * TT + t;
    ssq[i] = accq; dotv[i] = accd; cmean[i] = accs * (1.0f / MM);
}

// kA: temporal = 1 - std(smooth, ddof=1). Row staged to LDS once.
__global__ void kA_temporal(const float* __restrict__ cmean,
                            float* __restrict__ temporal) {
    const int b = blockIdx.x;
    const int tid = threadIdx.x;
    __shared__ __align__(16) float row_s[TT];
    __shared__ float red[256];
    __shared__ float mean_s;
    const float4* c4 = (const float4*)(cmean + (size_t)b * TT);
    float4* r4 = (float4*)row_s;
    for (int i = tid; i < TT / 4; i += 256) r4[i] = c4[i];
    __syncthreads();

    float s = 0.f;
    for (int t = tid; t < TT; t += 256) {
        float v = 0.f;
        int lo = t - 2 < 0 ? 0 : t - 2;
        int hi = t + 2 >= TT ? TT - 1 : t + 2;
        for (int j = lo; j <= hi; ++j) v += row_s[j];
        s += v / 5.0f;
    }
    red[tid] = s; __syncthreads();
    for (int o = 128; o > 0; o >>= 1) {
        if (tid < o) red[tid] += red[tid + o];
        __syncthreads();
    }
    if (tid == 0) mean_s = red[0] / (float)TT;
    __syncthreads();
    float mean = mean_s;
    float ss = 0.f;
    for (int t = tid; t < TT; t += 256) {
        float v = 0.f;
        int lo = t - 2 < 0 ? 0 : t - 2;
        int hi = t + 2 >= TT ? TT - 1 : t + 2;
        for (int j = lo; j <= hi; ++j) v += row_s[j];
        float sm = v / 5.0f - mean;
        ss += sm * sm;
    }
    red[tid] = ss; __syncthreads();
    for (int o = 128; o > 0; o >>= 1) {
        if (tid < o) red[tid] += red[tid + o];
        __syncthreads();
    }
    if (tid == 0) {
        float var = red[0] / (float)(TT - 1);
        temporal[b] = 1.0f - sqrtf(var);
    }
}

// kB: cons — same arithmetic as the passing version; additionally writes
// the Q4-interleaved copy for the scan (same value, extra store only).
__global__ void kB_cons(const float* __restrict__ ssq,
                        const float* __restrict__ dotv,
                        const float* __restrict__ spec,
                        const float* __restrict__ temporal,
                        const float* __restrict__ wraw,
                        float* __restrict__ cons,
                        float* __restrict__ consq) {
    const int idx = blockIdx.x * 256 + threadIdx.x;
    const int b = idx / TT;
    const int t = idx - b * TT;
    float x0 = wraw[0], x1 = wraw[1], x2 = wraw[2];
    float mx = fmaxf(x0, fmaxf(x1, x2));
    float e0 = expf(x0 - mx), e1 = expf(x1 - mx), e2 = expf(x2 - mx);
    float es = (e0 + e1) + e2;
    float w0 = e0 / es, w1 = e1 / es, w2 = e2 / es;
    float mel_sim, spec_sim;
    if (t == 0) { mel_sim = 0.f; spec_sim = 1.f; }
    else {
        float na = fmaxf(sqrtf(ssq[idx - 1]), 1e-8f);
        float nb = fmaxf(sqrtf(ssq[idx]),     1e-8f);
        float den = na * nb; asm volatile("" : "+v"(den));
        mel_sim = dotv[idx] / den;
        float d = fabsf(spec[idx] - spec[idx - 1]);
        spec_sim = 1.0f / (1.0f + d);
    }
    float pa = w0 * mel_sim;     asm volatile("" : "+v"(pa));
    float pb = w1 * spec_sim;    asm volatile("" : "+v"(pb));
    float pc = w2 * temporal[b]; asm volatile("" : "+v"(pc));
    float c = (pa + pb) + pc;
    cons[idx] = c;
    consq[((t >> 2) * 16 + b) * 4 + (t & 3)] = c;
}

// 4 chained adds: carry enters via P's last reg, leaves in d.
#define QCH(P, a, b, c, d) \
    "v_add_f32 v" a ", v" P ", v" a "\n\t" \
    "v_add_f32 v" b ", v" a ", v" b "\n\t" \
    "v_add_f32 v" c ", v" b ", v" c "\n\t" \
    "v_add_f32 v" d ", v" c ", v" d "\n\t"

// One SB (8 groups = 32 elems, 16 lanes lockstep): ONE vmcnt(32) wait
// (ring = 3 SBs x 16 ops; my 8 operand loads are 32 ops old — FIFO-exact),
// 32 chained adds (bitwise reference order), carry snapshot BEFORE the
// prefetch loads (round-5 WAR discipline), 8 Q4 stores (256 contiguous
// bytes each), 8 prefetch loads 24 groups ahead, pointer bumps.
#define SB8(a0,a1,a2,a3, b0,b1,b2,b3, c0,c1,c2,c3, d0,d1,d2,d3, \
            e0,e1,e2,e3, f0,f1,f2,f3, g0,g1,g2,g3, h0,h1,h2,h3) \
    "s_waitcnt vmcnt(32)\n\t" \
    QCH("43", a0, a1, a2, a3) \
    QCH(a3,   b0, b1, b2, b3) \
    QCH(b3,   c0, c1, c2, c3) \
    QCH(c3,   d0, d1, d2, d3) \
    QCH(d3,   e0, e1, e2, e3) \
    QCH(e3,   f0, f1, f2, f3) \
    QCH(f3,   g0, g1, g2, g3) \
    QCH(g3,   h0, h1, h2, h3) \
    "v_mov_b32 v43, v" h3 "\n\t" \
    "global_store_dwordx4 v40, v[" a0 ":" a3 "], %1 offset:0\n\t" \
    "global_store_dwordx4 v40, v[" b0 ":" b3 "], %1 offset:256\n\t" \
    "global_store_dwordx4 v40, v[" c0 ":" c3 "], %1 offset:512\n\t" \
    "global_store_dwordx4 v40, v[" d0 ":" d3 "], %1 offset:768\n\t" \
    "global_store_dwordx4 v40, v[" e0 ":" e3 "], %1 offset:1024\n\t" \
    "global_store_dwordx4 v40, v[" f0 ":" f3 "], %1 offset:1280\n\t" \
    "global_store_dwordx4 v40, v[" g0 ":" g3 "], %1 offset:1536\n\t" \
    "global_store_dwordx4 v40, v[" h0 ":" h3 "], %1 offset:1792\n\t" \
    "global_load_dwordx4 v[" a0 ":" a3 "], v42, %0 offset:0\n\t" \
    "global_load_dwordx4 v[" b0 ":" b3 "], v42, %0 offset:256\n\t" \
    "global_load_dwordx4 v[" c0 ":" c3 "], v42, %0 offset:512\n\t" \
    "global_load_dwordx4 v[" d0 ":" d3 "], v42, %0 offset:768\n\t" \
    "global_load_dwordx4 v[" e0 ":" e3 "], v42, %0 offset:1024\n\t" \
    "global_load_dwordx4 v[" f0 ":" f3 "], v42, %0 offset:1280\n\t" \
    "global_load_dwordx4 v[" g0 ":" g3 "], v42, %0 offset:1536\n\t" \
    "global_load_dwordx4 v[" h0 ":" h3 "], v42, %0 offset:1792\n\t" \
    "v_add_u32 v40, 0x800, v40\n\t" \
    "v_add_u32 v42, 0x800, v42\n\t"

// kC: 16-lane SIMT scan, 8-group SBs (375 waits instead of 750 — halved
// per-SB overhead), 24-group ring, + decoupled L2 warmers (waves 1-3,
// no barriers; round-25 neutral-to-slightly-positive).
__global__ void __launch_bounds__(256)
kC_scan16(const float* __restrict__ consq,
          float* __restrict__ CSq) {
    const int tid = threadIdx.x;
    if (tid >= 64) {
        // warmers: stream all of consq into the local XCD L2.
        const float4* s4 = (const float4*)consq;
        const int lane = tid - 64;
        for (int it = 0; it < 32; ++it) {
            float4 tmp[8];
#pragma unroll
            for (int i = 0; i < 8; ++i)
                tmp[i] = s4[(size_t)it * 1536 + lane + 192 * i];
#pragma unroll
            for (int i = 0; i < 8; ++i)
                asm volatile("" :: "v"(tmp[i].x), "v"(tmp[i].y),
                                   "v"(tmp[i].z), "v"(tmp[i].w));
        }
        return;
    }
    const int r = tid;
    if (r >= BB) return;
    uint32_t voff = (uint32_t)(r * 16);   // per-lane byte offset in a group
    asm volatile(
        "v_mov_b32 v40, %2\n\t"
        "v_mov_b32 v43, 0\n\t"
        // prologue: fill 24-quad ring (groups 0..23)
        "global_load_dwordx4 v[48:51],   v40, %0 offset:0\n\t"
        "global_load_dwordx4 v[52:55],   v40, %0 offset:256\n\t"
        "global_load_dwordx4 v[56:59],   v40, %0 offset:512\n\t"
        "global_load_dwordx4 v[60:63],   v40, %0 offset:768\n\t"
        "global_load_dwordx4 v[64:67],   v40, %0 offset:1024\n\t"
        "global_load_dwordx4 v[68:71],   v40, %0 offset:1280\n\t"
        "global_load_dwordx4 v[72:75],   v40, %0 offset:1536\n\t"
        "global_load_dwordx4 v[76:79],   v40, %0 offset:1792\n\t"
        "global_load_dwordx4 v[80:83],   v40, %0 offset:2048\n\t"
        "global_load_dwordx4 v[84:87],   v40, %0 offset:2304\n\t"
        "global_load_dwordx4 v[88:91],   v40, %0 offset:2560\n\t"
        "global_load_dwordx4 v[92:95],   v40, %0 offset:2816\n\t"
        "global_load_dwordx4 v[96:99],   v40, %0 offset:3072\n\t"
        "global_load_dwordx4 v[100:103], v40, %0 offset:3328\n\t"
        "global_load_dwordx4 v[104:107], v40, %0 offset:3584\n\t"
        "global_load_dwordx4 v[108:111], v40, %0 offset:3840\n\t"
        "v_add_u32 v41, 0x1000, v40\n\t"
        "global_load_dwordx4 v[112:115], v41, %0 offset:0\n\t"
        "global_load_dwordx4 v[116:119], v41, %0 offset:256\n\t"
        "global_load_dwordx4 v[120:123], v41, %0 offset:512\n\t"
        "global_load_dwordx4 v[124:127], v41, %0 offset:768\n\t"
        "global_load_dwordx4 v[128:131], v41, %0 offset:1024\n\t"
        "global_load_dwordx4 v[132:135], v41, %0 offset:1280\n\t"
        "global_load_dwordx4 v[136:139], v41, %0 offset:1536\n\t"
        "global_load_dwordx4 v[140:143], v41, %0 offset:1792\n\t"
        "v_add_u32 v42, 0x1800, v40\n\t"   // load base: 24 groups ahead
        "s_waitcnt vmcnt(0)\n\t"
        "s_mov_b32 s20, 125\n\t"           // 125 passes x 3 SB8 = 3000 groups
        "3:\n\t"
        SB8("48","49","50","51",   "52","53","54","55",
            "56","57","58","59",   "60","61","62","63",
            "64","65","66","67",   "68","69","70","71",
            "72","73","74","75",   "76","77","78","79")
        SB8("80","81","82","83",   "84","85","86","87",
            "88","89","90","91",   "92","93","94","95",
            "96","97","98","99",   "100","101","102","103",
            "104","105","106","107","108","109","110","111")
        SB8("112","113","114","115","116","117","118","119",
            "120","121","122","123","124","125","126","127",
            "128","129","130","131","132","133","134","135",
            "136","137","138","139","140","141","142","143")
        "s_sub_u32 s20, s20, 1\n\t"
        "s_cmp_lg_u32 s20, 0\n\t"
        "s_cbranch_scc1 3b\n\t"
        "s_waitcnt vmcnt(0)\n\t"
        :
        : "s"(consq), "s"(CSq), "v"(voff)
        : "v40", "v41", "v42", "v43",
          "v48", "v49", "v50", "v51", "v52", "v53", "v54", "v55",
          "v56", "v57", "v58", "v59", "v60", "v61", "v62", "v63",
          "v64", "v65", "v66", "v67", "v68", "v69", "v70", "v71",
          "v72", "v73", "v74", "v75", "v76", "v77", "v78", "v79",
          "v80", "v81", "v82", "v83", "v84", "v85", "v86", "v87",
          "v88", "v89", "v90", "v91", "v92", "v93", "v94", "v95",
          "v96", "v97", "v98", "v99", "v100", "v101", "v102", "v103",
          "v104", "v105", "v106", "v107", "v108", "v109", "v110", "v111",
          "v112", "v113", "v114", "v115", "v116", "v117", "v118", "v119",
          "v120", "v121", "v122", "v123", "v124", "v125", "v126", "v127",
          "v128", "v129", "v130", "v131", "v132", "v133", "v134", "v135",
          "v136", "v137", "v138", "v139", "v140", "v141", "v142", "v143",
          "s20", "scc", "memory");
}

// kD: flags ONLY — per-iteration "any nonzero adjustment" on the
// never-done trajectory. k_final recomputes step/cand (bitwise same).
__global__ void kD_flags(const float* __restrict__ cons,
                         const float* __restrict__ CSq,
                         const float* __restrict__ init,
                         unsigned int* __restrict__ counts) {
    const int idx = blockIdx.x * 256 + threadIdx.x;
    const int b = idx / TT;
    const int t = idx - b * TT;
    __shared__ unsigned sflag[5];
    if (threadIdx.x < 5) sflag[threadIdx.x] = 0u;
    __syncthreads();

    int lo = t - 2; if (lo < 0) lo = 0;
    int hi = t + 3; if (hi > TT) hi = TT;
    int uh = hi - 1;
    float csH = CSq[((uh >> 2) * 16 + b) * 4 + (uh & 3)];
    float csL = 0.f;
    if (lo > 0) {
        int ul = lo - 1;
        csL = CSq[((ul >> 2) * 16 + b) * 4 + (ul & 3)];
    }
    float local = (csH - csL) / (float)(hi - lo);
    float dir = (local > 0.7f) ? -0.1f : ((local < 0.4f) ? 0.1f : 0.0f);
    bool interior = (t >= 1) && (t <= TT - 2);
    float step = interior ? dir : 0.0f;
    float g = (t == 0) ? 0.f : fabsf(cons[idx] - cons[idx - 1]);
    float cand = (g > 0.15f) ? 1.f : 0.f;
    float r = init[idx];
    bool nz[5];
#pragma unroll
    for (int j = 0; j < 5; ++j) {
        float adj = (fmaxf(cand, r) > 0.5f) ? step : 0.0f;
        nz[j] = (adj != 0.0f);
        r = fminf(fmaxf(r + adj, 0.0f), 1.0f);
    }
    const int lane = threadIdx.x & 63;
#pragma unroll
    for (int j = 0; j < 5; ++j) {
        unsigned long long mb = __ballot(nz[j]);
        if (lane == 0 && mb) atomicOr(&sflag[j], 1u);   // LDS-scope, cheap
    }
    __syncthreads();
    if (threadIdx.x < 5 && sflag[threadIdx.x]) counts[threadIdx.x] = 1u;
}

// K_final: recompute step/cand (bitwise same as kD) and replay the 5-iter
// trajectory, freezing at the first iteration whose flag is 0.
__global__ void k_final(const float* __restrict__ cons,
                        const float* __restrict__ CSq,
                        const float* __restrict__ init,
                        const unsigned int* __restrict__ counts,
                        float* __restrict__ outp) {
    const int idx = blockIdx.x * 256 + threadIdx.x;
    const int b = idx / TT;
    const int t = idx - b * TT;

    int lo = t - 2; if (lo < 0) lo = 0;
    int hi = t + 3; if (hi > TT) hi = TT;
    int uh = hi - 1;
    float csH = CSq[((uh >> 2) * 16 + b) * 4 + (uh & 3)];
    float csL = 0.f;
    if (lo > 0) {
        int ul = lo - 1;
        csL = CSq[((ul >> 2) * 16 + b) * 4 + (ul & 3)];
    }
    float local = (csH - csL) / (float)(hi - lo);
    float dir = (local > 0.7f) ? -0.1f : ((local < 0.4f) ? 0.1f : 0.0f);
    bool interior = (t >= 1) && (t <= TT - 2);
    float step = interior ? dir : 0.0f;
    float g = (t == 0) ? 0.f : fabsf(cons[idx] - cons[idx - 1]);
    float cand = (g > 0.15f) ? 1.f : 0.f;

    float r = init[idx];
    unsigned c[5];
#pragma unroll
    for (int j = 0; j < 5; ++j) c[j] = counts[j];
#pragma unroll
    for (int j = 0; j < 5; ++j) {
        if (c[j] == 0u) break;
        float adj = (fmaxf(cand, r) > 0.5f) ? step : 0.0f;
        r = fminf(fmaxf(r + adj, 0.0f), 1.0f);
    }
    outp[idx] = r;
}

extern "C" void kernel_launch(void* const* d_in, const int* in_sizes, int n_in,
                              void* d_out, int out_size, void* d_ws, size_t ws_size,
                              hipStream_t stream) {
    const float* mel  = (const float*)d_in[0];
    const float* spec = (const float*)d_in[1];
    const float* init = (const float*)d_in[2];
    const float* wts  = (const float*)d_in[3];

    float* ws = (float*)d_ws;
    float* ssq   = ws;                 // 192000
    float* dotv  = ws + 192000;        // 192000
    float* cmean = ws + 384000;        // 192000
    float* cons  = ws + 576000;        // 192000 (row-major, for grads)
    float* consq = ws + 768000;        // 192000 (Q4-interleaved)
    float* CSq   = ws + 960000;        // 198144 (Q4; absorbs tail prefetch over-read)
    float* temporal = ws + 1158144;    // 16
    unsigned int* counts = (unsigned int*)(ws + 1158160); // 8 u32

    dim3 g1((TT + 255) / 256, BB);
    k1_colstats<<<g1, 256, 0, stream>>>(mel, ssq, dotv, cmean, counts);
    kA_temporal<<<BB, 256, 0, stream>>>(cmean, temporal);
    kB_cons<<<BT / 256, 256, 0, stream>>>(ssq, dotv, spec, temporal, wts, cons, consq);
    kC_scan16<<<1, 256, 0, stream>>>(consq, CSq);
    kD_flags<<<BT / 256, 256, 0, stream>>>(cons, CSq, init, counts);
    k_final<<<BT / 256, 256, 0, stream>>>(cons, CSq, init, counts, (float*)d_out);
}